// Round 12
// baseline (236.828 us; speedup 1.0000x reference)
//
#include <hip/hip_runtime.h>
#include <math.h>

#define G  300
#define NS 256
#define NR 4096
#define CT 32        // interleaved texel channels: 0-7 density, 8-31 app
#define SLABS 6      // row-slabs per axis for the joint sort key

typedef _Float16 half16_t;
typedef _Float16 h8 __attribute__((ext_vector_type(8)));

// ---------------------------------------------------------------------------
// Prep: interleave density(8ch) + app(24ch) planes into fp16 texels [i][y][x][c].
// Line tail (3*G texels) folded into the same grid.
// ---------------------------------------------------------------------------
__global__ __launch_bounds__(256) void prep_all(
    const float* __restrict__ dp, const float* __restrict__ ap,
    const float* __restrict__ dl, const float* __restrict__ al,
    half16_t* __restrict__ outp, half16_t* __restrict__ outl)
{
  int t = blockIdx.x * blockDim.x + threadIdx.x;
  if (t < 3 * G * G) {
    int x  = t % G;
    int yi = t / G;
    int y  = yi % G;
    int i  = yi / G;
    const float* dpp = dp + ((size_t)(i * 8) * G + y) * G + x;
    const float* app = ap + ((size_t)(i * 24) * G + y) * G + x;
    h8 v[4];
#pragma unroll
    for (int c = 0; c < 8; ++c) v[c >> 3][c & 7] = (half16_t)dpp[(size_t)c * G * G];
#pragma unroll
    for (int c = 0; c < 24; ++c) {
      int cc = c + 8;
      v[cc >> 3][cc & 7] = (half16_t)app[(size_t)c * G * G];
    }
    h8* o = (h8*)(outp + (size_t)t * CT);
#pragma unroll
    for (int m = 0; m < 4; ++m) o[m] = v[m];
  } else {
    int u = t - 3 * G * G;
    if (u < 3 * G) {
      int p = u % G;
      int i = u / G;
      h8 v[4];
#pragma unroll
      for (int c = 0; c < 8; ++c) v[c >> 3][c & 7] = (half16_t)dl[(i * 8 + c) * G + p];
#pragma unroll
      for (int c = 0; c < 24; ++c) {
        int cc = c + 8;
        v[cc >> 3][cc & 7] = (half16_t)al[(i * 24 + c) * G + p];
      }
      h8* o = (h8*)(outl + (size_t)u * CT);
#pragma unroll
      for (int m = 0; m < 4; ++m) o[m] = v[m];
    }
  }
}

// ---------------------------------------------------------------------------
// Main fused kernel — R8 structure verbatim, 128-thread blocks (2 rays).
//
// 2048 blocks x 128 thr = 2 waves; wave = one full ray. Quartet (4 lanes)
// per sample, 8 ch/lane (r==0: density, r=1..3: app).
//
// R11 post-mortem: request-diet falsified (lines were L1-hits; LDS staging
// net-negative). VALU invariant ~58 us/CU. The untested quadrant is R8's
// exact unrolled body at >6.5 resident waves. R12 changes ONE variable:
// block 256->128 (2 waves), grid 1024->2048. LDS 18.4 KB -> 8 blocks/CU,
// VGPR ~104 -> 16 waves/CU; supply 8 blocks/CU = 16 waves/CU (2x R8).
// Per-sample math bit-identical to R8 (sG staged xyz, lines via VMEM).
// Pre-commit: null result => serialized TA/L1 line service => structural
// floor; declare roofline.
// ---------------------------------------------------------------------------
__global__ __launch_bounds__(128) void tensorf_fused(
    const float* __restrict__ xyz, const float* __restrict__ zv,
    const half16_t* __restrict__ planes, const half16_t* __restrict__ lns,
    const float* __restrict__ dbw, const float* __restrict__ abw,
    const float* __restrict__ aabb, float* __restrict__ out)
{
  __shared__ float4 srgb[2][NS];       // 8 KB, wave-private (sigma,r,g,b)
  __shared__ float4 sG[2][NS];         // 8 KB, wave-private grid coords
  __shared__ unsigned char lst[2][NS]; // 512 B slab-sorted sample ids
  __shared__ float sW[3][128];         // 1.5 KB basis weights

  const int tid = threadIdx.x;
  for (int idx = tid; idx < 3 * 128; idx += 128) {
    int j = idx >> 7, c = idx & 127;
    float v = 0.f;
    if (c < 72) v = abw[j * 72 + c];
    else if (j == 0 && c < 96) v = dbw[c - 72];
    sW[j][c] = v;
  }

  const int wv   = tid >> 6;             // wave = ray slot (0..1)
  const int lane = tid & 63;
  const int ray  = (blockIdx.x << 1) + wv;
  const int q    = lane >> 2;            // quartet id (0..15)
  const int r    = lane & 3;             // channel group (8 ch each)

  const float a0x = aabb[0], a0y = aabb[1], a0z = aabb[2];
  const float ivx = 2.f / (aabb[3] - aabb[0]);
  const float ivy = 2.f / (aabb[4] - aabb[1]);
  const float ivz = 2.f / (aabb[5] - aabb[2]);

  // ---- binning pass: grid coords to LDS once; joint slab key per sample ---
  int key[4];
  {
    const float slabScale = (float)SLABS / (float)G;
#pragma unroll
    for (int j = 0; j < 4; ++j) {
      int s = (lane << 2) + j;
      const float* xp = xyz + ((size_t)ray * NS + s) * 3;
      float g0 = (xp[0] - a0x) * ivx - 1.f;
      float g1 = (xp[1] - a0y) * ivy - 1.f;
      float g2 = (xp[2] - a0z) * ivz - 1.f;
      sG[wv][s] = make_float4(g0, g1, g2, 0.f);
      float fy0 = (g1 + 1.f) * (0.5f * (G - 1));   // plane 0 row coord (axis 1)
      float fy1 = (g2 + 1.f) * (0.5f * (G - 1));   // planes 1,2 row coord (axis 2)
      int k0 = min(max((int)(fy0 * slabScale), 0), SLABS - 1);
      int k1 = min(max((int)(fy1 * slabScale), 0), SLABS - 1);
      key[j] = k0 * SLABS + k1;
    }
  }

  // ---- counting sort by key: single wave-uniform running offset -----------
  {
    const unsigned long long ltmask = (1ull << lane) - 1ull;
    int off = 0;
    for (int b = 0; b < SLABS * SLABS; ++b) {
#pragma unroll
      for (int j = 0; j < 4; ++j) {
        bool hit = (key[j] == b);
        unsigned long long m = __ballot(hit);
        if (hit) lst[wv][off + (int)__popcll(m & ltmask)] =
                   (unsigned char)((lane << 2) + j);
        off += (int)__popcll(m);
      }
    }
  }
  __syncthreads();   // sW (cross-wave) + lst/sG ordering

  const int MA[3] = {0, 0, 1};   // MAT_MODE first
  const int MB[3] = {1, 2, 2};   // MAT_MODE second
  const int MV[3] = {2, 1, 0};   // VEC_MODE
  const int ro = r * 8;

  // ---- gather: dense sweep in sorted order, unrolled 3-plane body ---------
  for (int base = 0; base < NS; base += 16) {
    int sid = lst[wv][base + q];
    float4 g4 = sG[wv][sid];
    float g[3] = {g4.x, g4.y, g4.z};

    float acc0 = 0.f, acc1 = 0.f, acc2 = 0.f;
#pragma unroll
    for (int i = 0; i < 3; ++i) {
      float fx = (g[MA[i]] + 1.f) * (0.5f * (G - 1));
      float fy = (g[MB[i]] + 1.f) * (0.5f * (G - 1));
      float ft = (g[MV[i]] + 1.f) * (0.5f * (G - 1));
      float x0f = floorf(fx), y0f = floorf(fy), t0f = floorf(ft);
      float wx = fx - x0f, wy = fy - y0f, wt = ft - t0f;
      int x0 = min(max((int)x0f, 0), G - 1);
      int y0 = min(max((int)y0f, 0), G - 1);
      int t0 = min(max((int)t0f, 0), G - 1);
      int x1 = min(x0 + 1, G - 1);
      int y1 = min(y0 + 1, G - 1);
      int t1 = min(t0 + 1, G - 1);

      const half16_t* pb = planes + (size_t)i * G * G * CT;
      h8 t00 = *(const h8*)(pb + ((size_t)(y0 * G + x0)) * CT + ro);
      h8 t01 = *(const h8*)(pb + ((size_t)(y0 * G + x1)) * CT + ro);
      h8 t10 = *(const h8*)(pb + ((size_t)(y1 * G + x0)) * CT + ro);
      h8 t11 = *(const h8*)(pb + ((size_t)(y1 * G + x1)) * CT + ro);
      const half16_t* lb = lns + (size_t)i * G * CT + ro;
      h8 l0 = *(const h8*)(lb + (size_t)t0 * CT);
      h8 l1 = *(const h8*)(lb + (size_t)t1 * CT);

      float w00 = (1.f - wx) * (1.f - wy), w01 = wx * (1.f - wy);
      float w10 = (1.f - wx) * wy,         w11 = wx * wy;
      float wl0 = 1.f - wt;

      float f[8];
#pragma unroll
      for (int k = 0; k < 8; ++k) {
        float pf = (float)t00[k] * w00 + (float)t01[k] * w01
                 + (float)t10[k] * w10 + (float)t11[k] * w11;
        float lf = (float)l0[k] * wl0 + (float)l1[k] * wt;
        f[k] = pf * lf;
      }

      int cb = (r == 0) ? (72 + i * 8) : (i * 24 + (r - 1) * 8);
      const float4* wp0 = (const float4*)&sW[0][cb];
      const float4* wp1 = (const float4*)&sW[1][cb];
      const float4* wp2 = (const float4*)&sW[2][cb];
      float4 wa, wb;
      wa = wp0[0]; wb = wp0[1];
      acc0 += wa.x * f[0] + wa.y * f[1] + wa.z * f[2] + wa.w * f[3]
            + wb.x * f[4] + wb.y * f[5] + wb.z * f[6] + wb.w * f[7];
      wa = wp1[0]; wb = wp1[1];
      acc1 += wa.x * f[0] + wa.y * f[1] + wa.z * f[2] + wa.w * f[3]
            + wb.x * f[4] + wb.y * f[5] + wb.z * f[6] + wb.w * f[7];
      wa = wp2[0]; wb = wp2[1];
      acc2 += wa.x * f[0] + wa.y * f[1] + wa.z * f[2] + wa.w * f[3]
            + wb.x * f[4] + wb.y * f[5] + wb.z * f[6] + wb.w * f[7];
    }

    // pack (sigma_feat, r, g, b) and reduce across the quartet
    float4 v;
    v.x = (r == 0) ? acc0 : 0.f;
    v.y = (r == 0) ? 0.f : acc0;
    v.z = (r == 0) ? 0.f : acc1;
    v.w = (r == 0) ? 0.f : acc2;
#pragma unroll
    for (int m = 1; m <= 2; m <<= 1) {
      v.x += __shfl_xor(v.x, m);
      v.y += __shfl_xor(v.y, m);
      v.z += __shfl_xor(v.z, m);
      v.w += __shfl_xor(v.w, m);
    }
    if (r == 0) srgb[wv][sid] = v;   // each sample written exactly once
  }
  __syncthreads();

  // ---- per-ray transmittance scan: lane handles samples lane*4 .. +3 ------
  const float* zp = zv + (size_t)ray * NS + (lane << 2);
  float4 z4 = *(const float4*)zp;
  float znext = __shfl_down(z4.x, 1);
  float d[4];
  d[0] = z4.y - z4.x;
  d[1] = z4.z - z4.y;
  d[2] = z4.w - z4.z;
  d[3] = (lane == 63) ? d[2] : (znext - z4.w);

  float4 c[4];
  float al[4];
  float tl = 1.f;
#pragma unroll
  for (int j = 0; j < 4; ++j) {
    c[j] = srgb[wv][(lane << 2) + j];
    float vs = c[j].x - 10.0f;  // DENSITY_SHIFT
    float sp = (vs > 0.f) ? (vs + log1pf(expf(-vs))) : log1pf(expf(vs));
    al[j] = 1.f - expf(-sp * (d[j] * 25.0f));  // DISTANCE_SCALE
    tl *= (1.f - al[j] + 1e-10f);
  }
  float incl = tl;
#pragma unroll
  for (int off = 1; off < 64; off <<= 1) {
    float pp = __shfl_up(incl, off);
    if (lane >= off) incl *= pp;
  }
  float T = __shfl_up(incl, 1);
  if (lane == 0) T = 1.f;

  float ar = 0.f, ag = 0.f, ab = 0.f;
#pragma unroll
  for (int j = 0; j < 4; ++j) {
    float w = al[j] * T;
    ar += w * c[j].y;
    ag += w * c[j].z;
    ab += w * c[j].w;
    T *= (1.f - al[j] + 1e-10f);
  }
#pragma unroll
  for (int off = 32; off > 0; off >>= 1) {
    ar += __shfl_down(ar, off);
    ag += __shfl_down(ag, off);
    ab += __shfl_down(ab, off);
  }
  if (lane == 0) {
    out[ray * 3 + 0] = ar;
    out[ray * 3 + 1] = ag;
    out[ray * 3 + 2] = ab;
  }
}

// ---------------------------------------------------------------------------
extern "C" void kernel_launch(void* const* d_in, const int* in_sizes, int n_in,
                              void* d_out, int out_size, void* d_ws, size_t ws_size,
                              hipStream_t stream)
{
  const float* xyz  = (const float*)d_in[0];
  // d_in[1] = viewdirs (unused by reference output path)
  const float* zv   = (const float*)d_in[2];
  const float* dp   = (const float*)d_in[3];
  const float* dl   = (const float*)d_in[4];
  const float* ap   = (const float*)d_in[5];
  const float* al   = (const float*)d_in[6];
  const float* dbw  = (const float*)d_in[7];
  const float* abw  = (const float*)d_in[8];
  const float* aabb = (const float*)d_in[9];
  float* outp = (float*)d_out;

  half16_t* planes16 = (half16_t*)d_ws;                    // 3*300*300*32 halves = 17.28 MB
  half16_t* lines16  = planes16 + (size_t)3 * G * G * CT;  // 28800 halves

  hipLaunchKernelGGL(prep_all, dim3((3 * G * G + 3 * G + 255) / 256), dim3(256), 0, stream,
                     dp, ap, dl, al, planes16, lines16);
  hipLaunchKernelGGL(tensorf_fused, dim3(NR / 2), dim3(128), 0, stream,
                     xyz, zv, planes16, lines16, dbw, abw, aabb, outp);
}

// Round 13
// 215.439 us; speedup vs baseline: 1.0993x; 1.0993x over previous
//
#include <hip/hip_runtime.h>
#include <math.h>

#define G  300
#define NS 256
#define NR 4096
#define CT 32        // interleaved texel channels: 0-7 density, 8-31 app
#define SLABS 6      // row-slabs per axis: 50 rows = 0.96 MB; live set 3 slabs = 2.9 MB

typedef _Float16 half16_t;
typedef _Float16 h8 __attribute__((ext_vector_type(8)));

// ---------------------------------------------------------------------------
// Prep: interleave density(8ch) + app(24ch) planes into fp16 texels [i][y][x][c].
// Line tail (3*G texels) folded into the same grid.
// ---------------------------------------------------------------------------
__global__ __launch_bounds__(256) void prep_all(
    const float* __restrict__ dp, const float* __restrict__ ap,
    const float* __restrict__ dl, const float* __restrict__ al,
    half16_t* __restrict__ outp, half16_t* __restrict__ outl)
{
  int t = blockIdx.x * blockDim.x + threadIdx.x;
  if (t < 3 * G * G) {
    int x  = t % G;
    int yi = t / G;
    int y  = yi % G;
    int i  = yi / G;
    const float* dpp = dp + ((size_t)(i * 8) * G + y) * G + x;
    const float* app = ap + ((size_t)(i * 24) * G + y) * G + x;
    h8 v[4];
#pragma unroll
    for (int c = 0; c < 8; ++c) v[c >> 3][c & 7] = (half16_t)dpp[(size_t)c * G * G];
#pragma unroll
    for (int c = 0; c < 24; ++c) {
      int cc = c + 8;
      v[cc >> 3][cc & 7] = (half16_t)app[(size_t)c * G * G];
    }
    h8* o = (h8*)(outp + (size_t)t * CT);
#pragma unroll
    for (int m = 0; m < 4; ++m) o[m] = v[m];
  } else {
    int u = t - 3 * G * G;
    if (u < 3 * G) {
      int p = u % G;
      int i = u / G;
      h8 v[4];
#pragma unroll
      for (int c = 0; c < 8; ++c) v[c >> 3][c & 7] = (half16_t)dl[(i * 8 + c) * G + p];
#pragma unroll
      for (int c = 0; c < 24; ++c) {
        int cc = c + 8;
        v[cc >> 3][cc & 7] = (half16_t)al[(i * 24 + c) * G + p];
      }
      h8* o = (h8*)(outl + (size_t)u * CT);
#pragma unroll
      for (int m = 0; m < 4; ++m) o[m] = v[m];
    }
  }
}

// ---------------------------------------------------------------------------
// Main fused kernel — R8 configuration, restored as the measured optimum.
//
// 1024 blocks x 256 thr = 4 waves; wave = one full ray. Quartet (4 lanes)
// per sample, 8 ch/lane (r==0: density, r=1..3: app).
//
// Session ledger (R0-R12): VALU work invariant ~139K cyc/CU (~58 us);
// 12 distinct 64B lines/sample is the bilinear minimum (texel = 1 line);
// occupancy lever null in 3 regimes; request-diet (lines->LDS) negative
// (lines are L1-hits); miss-volume reduction via joint-slab sort kept
// (FETCH 461->308 MB, -12 us). Every neighborhood move from this config
// measured slower: 2-wave blocks (157), rolled loop+split ray (129),
// lines-in-LDS (130), +sXyz 1-block/CU (153). This is the empirical
// optimum of the design space: ~120 us fused, absmax 2.980232e-08.
// ---------------------------------------------------------------------------
__global__ __launch_bounds__(256) void tensorf_fused(
    const float* __restrict__ xyz, const float* __restrict__ zv,
    const half16_t* __restrict__ planes, const half16_t* __restrict__ lns,
    const float* __restrict__ dbw, const float* __restrict__ abw,
    const float* __restrict__ aabb, float* __restrict__ out)
{
  __shared__ float4 srgb[4][NS];       // 16 KB, wave-private (sigma,r,g,b)
  __shared__ float4 sG[4][NS];         // 16 KB, wave-private grid coords (g0,g1,g2,-)
  __shared__ unsigned char lst[4][NS]; // 1 KB, slab-sorted sample ids
  __shared__ float sW[3][128];         // 1.5 KB basis weights

  const int tid = threadIdx.x;
  for (int idx = tid; idx < 3 * 128; idx += 256) {
    int j = idx >> 7, c = idx & 127;
    float v = 0.f;
    if (c < 72) v = abw[j * 72 + c];
    else if (j == 0 && c < 96) v = dbw[c - 72];
    sW[j][c] = v;
  }

  const int wv   = tid >> 6;
  const int lane = tid & 63;
  const int ray  = (blockIdx.x << 2) + wv;
  const int q    = lane >> 2;            // quartet id (0..15)
  const int r    = lane & 3;             // channel group (8 ch each)

  const float a0x = aabb[0], a0y = aabb[1], a0z = aabb[2];
  const float ivx = 2.f / (aabb[3] - aabb[0]);
  const float ivy = 2.f / (aabb[4] - aabb[1]);
  const float ivz = 2.f / (aabb[5] - aabb[2]);

  // ---- binning pass: grid coords to LDS once; joint slab key per sample ---
  int key[4];
  {
    const float slabScale = (float)SLABS / (float)G;
#pragma unroll
    for (int j = 0; j < 4; ++j) {
      int s = (lane << 2) + j;
      const float* xp = xyz + ((size_t)ray * NS + s) * 3;
      float g0 = (xp[0] - a0x) * ivx - 1.f;
      float g1 = (xp[1] - a0y) * ivy - 1.f;
      float g2 = (xp[2] - a0z) * ivz - 1.f;
      sG[wv][s] = make_float4(g0, g1, g2, 0.f);
      float fy0 = (g1 + 1.f) * (0.5f * (G - 1));   // plane 0 row coord (axis 1)
      float fy1 = (g2 + 1.f) * (0.5f * (G - 1));   // planes 1,2 row coord (axis 2)
      int k0 = min(max((int)(fy0 * slabScale), 0), SLABS - 1);
      int k1 = min(max((int)(fy1 * slabScale), 0), SLABS - 1);
      key[j] = k0 * SLABS + k1;
    }
  }

  // ---- counting sort by key: single wave-uniform running offset -----------
  {
    const unsigned long long ltmask = (1ull << lane) - 1ull;
    int off = 0;
    for (int b = 0; b < SLABS * SLABS; ++b) {
#pragma unroll
      for (int j = 0; j < 4; ++j) {
        bool hit = (key[j] == b);
        unsigned long long m = __ballot(hit);
        if (hit) lst[wv][off + (int)__popcll(m & ltmask)] =
                   (unsigned char)((lane << 2) + j);
        off += (int)__popcll(m);
      }
    }
  }
  __syncthreads();   // sW (cross-wave) + lst/sG ordering

  const int MA[3] = {0, 0, 1};   // MAT_MODE first
  const int MB[3] = {1, 2, 2};   // MAT_MODE second
  const int MV[3] = {2, 1, 0};   // VEC_MODE
  const int ro = r * 8;

  // ---- gather: dense sweep in sorted order, R0 body -----------------------
  for (int base = 0; base < NS; base += 16) {
    int sid = lst[wv][base + q];
    float4 g4 = sG[wv][sid];
    float g[3] = {g4.x, g4.y, g4.z};

    float acc0 = 0.f, acc1 = 0.f, acc2 = 0.f;
#pragma unroll
    for (int i = 0; i < 3; ++i) {
      float fx = (g[MA[i]] + 1.f) * (0.5f * (G - 1));
      float fy = (g[MB[i]] + 1.f) * (0.5f * (G - 1));
      float ft = (g[MV[i]] + 1.f) * (0.5f * (G - 1));
      float x0f = floorf(fx), y0f = floorf(fy), t0f = floorf(ft);
      float wx = fx - x0f, wy = fy - y0f, wt = ft - t0f;
      int x0 = min(max((int)x0f, 0), G - 1);
      int y0 = min(max((int)y0f, 0), G - 1);
      int t0 = min(max((int)t0f, 0), G - 1);
      int x1 = min(x0 + 1, G - 1);
      int y1 = min(y0 + 1, G - 1);
      int t1 = min(t0 + 1, G - 1);

      const half16_t* pb = planes + (size_t)i * G * G * CT;
      h8 t00 = *(const h8*)(pb + ((size_t)(y0 * G + x0)) * CT + ro);
      h8 t01 = *(const h8*)(pb + ((size_t)(y0 * G + x1)) * CT + ro);
      h8 t10 = *(const h8*)(pb + ((size_t)(y1 * G + x0)) * CT + ro);
      h8 t11 = *(const h8*)(pb + ((size_t)(y1 * G + x1)) * CT + ro);
      const half16_t* lb = lns + (size_t)i * G * CT + ro;
      h8 l0 = *(const h8*)(lb + (size_t)t0 * CT);
      h8 l1 = *(const h8*)(lb + (size_t)t1 * CT);

      float w00 = (1.f - wx) * (1.f - wy), w01 = wx * (1.f - wy);
      float w10 = (1.f - wx) * wy,         w11 = wx * wy;
      float wl0 = 1.f - wt;

      float f[8];
#pragma unroll
      for (int k = 0; k < 8; ++k) {
        float pf = (float)t00[k] * w00 + (float)t01[k] * w01
                 + (float)t10[k] * w10 + (float)t11[k] * w11;
        float lf = (float)l0[k] * wl0 + (float)l1[k] * wt;
        f[k] = pf * lf;
      }

      int cb = (r == 0) ? (72 + i * 8) : (i * 24 + (r - 1) * 8);
      const float4* wp0 = (const float4*)&sW[0][cb];
      const float4* wp1 = (const float4*)&sW[1][cb];
      const float4* wp2 = (const float4*)&sW[2][cb];
      float4 wa, wb;
      wa = wp0[0]; wb = wp0[1];
      acc0 += wa.x * f[0] + wa.y * f[1] + wa.z * f[2] + wa.w * f[3]
            + wb.x * f[4] + wb.y * f[5] + wb.z * f[6] + wb.w * f[7];
      wa = wp1[0]; wb = wp1[1];
      acc1 += wa.x * f[0] + wa.y * f[1] + wa.z * f[2] + wa.w * f[3]
            + wb.x * f[4] + wb.y * f[5] + wb.z * f[6] + wb.w * f[7];
      wa = wp2[0]; wb = wp2[1];
      acc2 += wa.x * f[0] + wa.y * f[1] + wa.z * f[2] + wa.w * f[3]
            + wb.x * f[4] + wb.y * f[5] + wb.z * f[6] + wb.w * f[7];
    }

    // pack (sigma_feat, r, g, b) and reduce across the quartet
    float4 v;
    v.x = (r == 0) ? acc0 : 0.f;
    v.y = (r == 0) ? 0.f : acc0;
    v.z = (r == 0) ? 0.f : acc1;
    v.w = (r == 0) ? 0.f : acc2;
#pragma unroll
    for (int m = 1; m <= 2; m <<= 1) {
      v.x += __shfl_xor(v.x, m);
      v.y += __shfl_xor(v.y, m);
      v.z += __shfl_xor(v.z, m);
      v.w += __shfl_xor(v.w, m);
    }
    if (r == 0) srgb[wv][sid] = v;   // each sample written exactly once
  }
  __syncthreads();

  // ---- per-ray transmittance scan: lane handles samples lane*4 .. +3 ------
  const float* zp = zv + (size_t)ray * NS + (lane << 2);
  float4 z4 = *(const float4*)zp;
  float znext = __shfl_down(z4.x, 1);
  float d[4];
  d[0] = z4.y - z4.x;
  d[1] = z4.z - z4.y;
  d[2] = z4.w - z4.z;
  d[3] = (lane == 63) ? d[2] : (znext - z4.w);

  float4 c[4];
  float al[4];
  float tl = 1.f;
#pragma unroll
  for (int j = 0; j < 4; ++j) {
    c[j] = srgb[wv][(lane << 2) + j];
    float vs = c[j].x - 10.0f;  // DENSITY_SHIFT
    float sp = (vs > 0.f) ? (vs + log1pf(expf(-vs))) : log1pf(expf(vs));
    al[j] = 1.f - expf(-sp * (d[j] * 25.0f));  // DISTANCE_SCALE
    tl *= (1.f - al[j] + 1e-10f);
  }
  float incl = tl;
#pragma unroll
  for (int off = 1; off < 64; off <<= 1) {
    float pp = __shfl_up(incl, off);
    if (lane >= off) incl *= pp;
  }
  float T = __shfl_up(incl, 1);
  if (lane == 0) T = 1.f;

  float ar = 0.f, ag = 0.f, ab = 0.f;
#pragma unroll
  for (int j = 0; j < 4; ++j) {
    float w = al[j] * T;
    ar += w * c[j].y;
    ag += w * c[j].z;
    ab += w * c[j].w;
    T *= (1.f - al[j] + 1e-10f);
  }
#pragma unroll
  for (int off = 32; off > 0; off >>= 1) {
    ar += __shfl_down(ar, off);
    ag += __shfl_down(ag, off);
    ab += __shfl_down(ab, off);
  }
  if (lane == 0) {
    out[ray * 3 + 0] = ar;
    out[ray * 3 + 1] = ag;
    out[ray * 3 + 2] = ab;
  }
}

// ---------------------------------------------------------------------------
extern "C" void kernel_launch(void* const* d_in, const int* in_sizes, int n_in,
                              void* d_out, int out_size, void* d_ws, size_t ws_size,
                              hipStream_t stream)
{
  const float* xyz  = (const float*)d_in[0];
  // d_in[1] = viewdirs (unused by reference output path)
  const float* zv   = (const float*)d_in[2];
  const float* dp   = (const float*)d_in[3];
  const float* dl   = (const float*)d_in[4];
  const float* ap   = (const float*)d_in[5];
  const float* al   = (const float*)d_in[6];
  const float* dbw  = (const float*)d_in[7];
  const float* abw  = (const float*)d_in[8];
  const float* aabb = (const float*)d_in[9];
  float* outp = (float*)d_out;

  half16_t* planes16 = (half16_t*)d_ws;                    // 3*300*300*32 halves = 17.28 MB
  half16_t* lines16  = planes16 + (size_t)3 * G * G * CT;  // 28800 halves

  hipLaunchKernelGGL(prep_all, dim3((3 * G * G + 3 * G + 255) / 256), dim3(256), 0, stream,
                     dp, ap, dl, al, planes16, lines16);
  hipLaunchKernelGGL(tensorf_fused, dim3(NR / 4), dim3(256), 0, stream,
                     xyz, zv, planes16, lines16, dbw, abw, aabb, outp);
}